// Round 11
// baseline (1131.146 us; speedup 1.0000x reference)
//
#include <hip/hip_runtime.h>
#include <math.h>

namespace {

constexpr int BTOT = 131072;
constexpr int HN = 24;
constexpr int NO = 24;
constexpr int NSTEPS = 23;
constexpr int WIH_STRIDE = 100;

// XLA:GPU(ROCm) model: exp/tanh are __ocml_exp_f32/__ocml_tanh_f32 == the
// native expf/tanhf on this chip. logistic_expander: 1/(1+exp(-x)).
__device__ __forceinline__ float xsig(float x) {
#pragma clang fp contract(off)
  return 1.0f / (1.0f + expf(-x));
}

// XLA:GPU row-reduce, row size 24 (pow2-padded to 32 lanes, init 0):
// shuffle-down tree offsets 16,8,4,2,1.
// Lanewise: L_j = (x_j + x_{j+16}) + x_{j+8}  (j=0..7; x_{24..31}=0 exact)
// Horizontal: ((L0+L4)+(L2+L6)) + ((L1+L5)+(L3+L7))
__device__ __forceinline__ float vsum24(const float* x) {
#pragma clang fp contract(off)
  float L[8];
#pragma unroll
  for (int j = 0; j < 8; ++j) L[j] = (x[j] + x[j + 16]) + x[j + 8];
  float b0 = L[0] + L[4];
  float b1 = L[1] + L[5];
  float b2 = L[2] + L[6];
  float b3 = L[3] + L[7];
  return (b0 + b2) + (b1 + b3);
}

// XLA:GPU row-reduce, row size n<=11 (pow2-padded to 16 lanes, init 0):
// shuffle tree offsets 8,4,2,1 over zero-padded lanes (x+0 exact).
__device__ __forceinline__ float vsumN(const float* x, int n) {
#pragma clang fp contract(off)
  float t[16];
#pragma unroll
  for (int l = 0; l < 16; ++l) t[l] = (l < n) ? x[l] : 0.f;
  float a[8], b[4], c[2];
#pragma unroll
  for (int l = 0; l < 8; ++l) a[l] = t[l] + t[l + 8];
#pragma unroll
  for (int l = 0; l < 4; ++l) b[l] = a[l] + a[l + 4];
#pragma unroll
  for (int l = 0; l < 2; ++l) c[l] = b[l] + b[l + 2];
  return c[0] + c[1];
}

// jax.lax.associative_scan(add) exact clone for n in [1,11] (verified vs
// jax _scan recursion for every n).
__device__ __forceinline__ void ascan11(float* x, int n) {
#pragma clang fp contract(off)
  if (n < 2) return;
  const int m1 = n >> 1;
  float r1[5];
#pragma unroll
  for (int i = 0; i < 5; ++i)
    if (2 * i + 1 < n) r1[i] = x[2 * i] + x[2 * i + 1];
  float r2[2] = {0.f, 0.f};
#pragma unroll
  for (int i = 0; i < 2; ++i)
    if (2 * i + 1 < m1) r2[i] = r1[2 * i] + r1[2 * i + 1];
  const int m2 = m1 >> 1;
  float s2[2];
  s2[0] = r2[0];
  s2[1] = (m2 == 2) ? (r2[0] + r2[1]) : r2[1];
  float s1[5];
  s1[0] = r1[0];
  if (1 < m1) s1[1] = s2[0];
  if (2 < m1) s1[2] = s2[0] + r1[2];
  if (3 < m1) s1[3] = s2[1];
  if (4 < m1) s1[4] = s2[1] + r1[4];
  float o[11];
  o[0] = x[0];
#pragma unroll
  for (int i = 0; i < 5; ++i) {
    if (2 * i + 1 < n) o[2 * i + 1] = s1[i];
    if (2 * i + 2 < n) o[2 * i + 2] = s1[i] + x[2 * i + 2];
  }
#pragma unroll
  for (int i = 0; i < 11; ++i)
    if (i < n) x[i] = o[i];
}

__global__ __launch_bounds__(256) void policy_kernel(
    const float* __restrict__ W_ih, const float* __restrict__ W_hh,
    const float* __restrict__ b_ih, const float* __restrict__ b_hh,
    const float* __restrict__ W_lin, const float* __restrict__ b_lin,
    const float* __restrict__ rand_u, float* __restrict__ out) {
#pragma clang fp contract(off)
  __shared__ __align__(16) float s_wih[23 * WIH_STRIDE];
  for (int t = threadIdx.x; t < 23 * 96; t += 256) {
    const int col = t / 96;
    const int r = t - col * 96;
    s_wih[col * WIH_STRIDE + r] = W_ih[((r & 3) * 24 + (r >> 2)) * NO + col];
  }
  __syncthreads();

  const int e = blockIdx.x * 256 + threadIdx.x;
  float* actions = out;                    // [B][24]
  float* probs = out + (size_t)BTOT * NO;  // [B][23]

  float h[HN], c[HN];
#pragma unroll
  for (int k = 0; k < HN; ++k) { h[k] = 0.f; c[k] = 0.f; }

  int x_idx = -1;  // -1 => x all zeros (first step)
  int step = 0;
  actions[(size_t)e * NO + 23] = 0.0f;

#pragma unroll 1
  for (int counter = 0; counter < 12; ++counter) {
#pragma unroll 1
    for (int sub = (counter == 0) ? 1 : 0; sub < 2; ++sub) {
      // ===== LSTM cell: rocBLAS-style ascending-k single-chain FMA dots ====
      const int xcol = (x_idx < 0) ? 0 : x_idx;
      const bool hasx = (x_idx >= 0);
      float hn[HN];
#pragma unroll
      for (int j = 0; j < HN; ++j) {
        const float4 wv =
            *reinterpret_cast<const float4*>(&s_wih[xcol * WIH_STRIDE + j * 4]);
        float ai = 0.f, af = 0.f, ag = 0.f, ao = 0.f;
#pragma unroll
        for (int k = 0; k < HN; ++k) {
          const float hk = h[k];
          ai = fmaf(W_hh[(j)*HN + k], hk, ai);
          af = fmaf(W_hh[(j + 24) * HN + k], hk, af);
          ag = fmaf(W_hh[(j + 48) * HN + k], hk, ag);
          ao = fmaf(W_hh[(j + 72) * HN + k], hk, ao);
        }
        const float gi = (((hasx ? wv.x : 0.f) + ai) + b_ih[j]) + b_hh[j];
        const float gf = (((hasx ? wv.y : 0.f) + af) + b_ih[j + 24]) + b_hh[j + 24];
        const float gg = (((hasx ? wv.z : 0.f) + ag) + b_ih[j + 48]) + b_hh[j + 48];
        const float go = (((hasx ? wv.w : 0.f) + ao) + b_ih[j + 72]) + b_hh[j + 72];
        const float t1 = xsig(gf) * c[j];
        const float t2 = xsig(gi) * tanhf(gg);
        const float c2 = t1 + t2;
        c[j] = c2;
        hn[j] = xsig(go) * tanhf(c2);
      }
#pragma unroll
      for (int j = 0; j < HN; ++j) h[j] = hn[j];

      // ===== p = softmax(h @ W_lin.T + b_lin): GPU shuffle-tree sum =====
      float p[NO];
#pragma unroll
      for (int o = 0; o < NO; ++o) {
        float a = 0.f;
#pragma unroll
        for (int k = 0; k < HN; ++k) a = fmaf(W_lin[o * HN + k], h[k], a);
        p[o] = a + b_lin[o];
      }
      float m = p[0];
#pragma unroll
      for (int o = 1; o < NO; ++o) m = fmaxf(m, p[o]);
#pragma unroll
      for (int o = 0; o < NO; ++o) p[o] = expf(p[o] - m);
      const float ssum = vsum24(p);
#pragma unroll
      for (int o = 0; o < NO; ++o) p[o] = p[o] / ssum;

      // ===== slice softmax (shuffle-tree sum) + tree cumsum sample =====
      const int count = (sub == 0) ? counter : 11;
      const int add = (sub == 0) ? 12 : 1;
      float q[11];
#pragma unroll
      for (int jj = 0; jj < 11; ++jj) q[jj] = (sub == 0) ? p[12 + jj] : p[jj];

      const float u = rand_u[(size_t)step * BTOT + e];
      float m2 = q[0];
#pragma unroll
      for (int jj = 1; jj < 11; ++jj)
        if (jj < count) m2 = fmaxf(m2, q[jj]);
#pragma unroll
      for (int jj = 0; jj < 11; ++jj)
        if (jj < count) q[jj] = expf(q[jj] - m2);
      const float qsum = vsumN(q, count);
      float dag[11];
#pragma unroll
      for (int jj = 0; jj < 11; ++jj)
        dag[jj] = (jj < count) ? (q[jj] / qsum) : 0.f;

      float cs[11];
#pragma unroll
      for (int jj = 0; jj < 11; ++jj) cs[jj] = dag[jj];
      ascan11(cs, count);  // jax associative_scan tree

      int idx = -1;
      float pr = 0.f;
#pragma unroll
      for (int jj = 0; jj < 11; ++jj)
        if (jj < count) {
          if (idx < 0 && cs[jj] > u) { idx = jj; pr = dag[jj]; }
        }
      if (idx < 0) { idx = 0; pr = dag[0]; }  // argmax(all False) = 0

      const int sel = idx + add;
      actions[(size_t)e * NO + step] = (float)sel;
      probs[(size_t)e * NSTEPS + step] = (float)pr;
      x_idx = sel;
      ++step;
    }
  }
}

}  // namespace

extern "C" void kernel_launch(void* const* d_in, const int* in_sizes, int n_in,
                              void* d_out, int out_size, void* d_ws, size_t ws_size,
                              hipStream_t stream) {
  const float* W_ih = (const float*)d_in[0];
  const float* W_hh = (const float*)d_in[1];
  const float* b_ih = (const float*)d_in[2];
  const float* b_hh = (const float*)d_in[3];
  const float* W_lin = (const float*)d_in[4];
  const float* b_lin = (const float*)d_in[5];
  const float* rand_u = (const float*)d_in[6];
  float* out = (float*)d_out;
  policy_kernel<<<dim3(BTOT / 256), dim3(256), 0, stream>>>(
      W_ih, W_hh, b_ih, b_hh, W_lin, b_lin, rand_u, out);
}